// Round 7
// baseline (186.625 us; speedup 1.0000x reference)
//
#include <hip/hip_runtime.h>
#include <stdint.h>

#pragma clang fp contract(off)

#define NMS_B 8
#define NMS_N 4096
#define NMS_NW 64       // 64-bit words per suppression row
#define ROIS 256

typedef unsigned long long u64;
typedef unsigned int u32;

__device__ __forceinline__ u64 rdlane_u64(u64 v, int l) {
    u32 lo = (u32)__builtin_amdgcn_readlane((int)(u32)v, l);
    u32 hi = (u32)__builtin_amdgcn_readlane((int)(u32)(v >> 32), l);
    return ((u64)hi << 32) | lo;
}
__device__ __forceinline__ u64 rdfirst_u64(u64 v) {
    u32 lo = (u32)__builtin_amdgcn_readfirstlane((int)(u32)v);
    u32 hi = (u32)__builtin_amdgcn_readfirstlane((int)(u32)(v >> 32));
    return ((u64)hi << 32) | lo;
}
__device__ __forceinline__ int lds_slot(int e) { return e + (e >> 2); }  // 4-way max bank aliasing

// ---------------------------------------------------------------------------
// K1a: local bitonic sort of 1024-element chunks (4 chunks/batch, 32 blocks).
// key = (~score_bits)<<32 | GLOBAL idx; direction bits use global e, so the
// result is bit-identical to the monolithic bitonic after its k=1024 stage.
// ---------------------------------------------------------------------------
__global__ __launch_bounds__(256) void nms_sort_local(
        const float* __restrict__ in, u64* __restrict__ keyb) {
    __shared__ u64 sm[1280];                   // slot(1023)=1278, 10 KB
    const int b = blockIdx.y, c = blockIdx.x, t = threadIdx.x;
    const int ebase = c * 1024;
    u64 key[4];

    #pragma unroll
    for (int r = 0; r < 4; ++r) {
        int e = ebase + 4 * t + r;
        float s = in[((size_t)b * NMS_N + e) * 5];
        key[r] = ((u64)(~__float_as_uint(s)) << 32) | (u32)e;
    }

    for (int k = 2; k <= 1024; k <<= 1) {
        int j = k >> 1;
        if (j >= 256) {
            #pragma unroll
            for (int r = 0; r < 4; ++r) sm[lds_slot(4 * t + r)] = key[r];
            __syncthreads();
            for (; j >= 256; j >>= 1) {
                for (int el = t; el < 1024; el += 256) {
                    int p = el ^ j;
                    if (p > el) {
                        u64 a = sm[lds_slot(el)], cc = sm[lds_slot(p)];
                        bool up = (((ebase + el) & k) == 0);
                        if ((a > cc) == up) { sm[lds_slot(el)] = cc; sm[lds_slot(p)] = a; }
                    }
                }
                __syncthreads();
            }
            #pragma unroll
            for (int r = 0; r < 4; ++r) key[r] = sm[lds_slot(4 * t + r)];
        }
        for (; j >= 4; j >>= 1) {              // cross-lane via shfl_xor
            int d = j >> 2;
            #pragma unroll
            for (int r = 0; r < 4; ++r) {
                int e = ebase + 4 * t + r;
                u64 mine = key[r];
                u64 part = __shfl_xor(mine, d, 64);
                bool up = ((e & k) == 0);
                bool lower = ((e & j) == 0);
                u64 mn = (mine < part) ? mine : part;
                u64 mx = (mine < part) ? part : mine;
                key[r] = (up == lower) ? mn : mx;
            }
        }
        for (; j >= 1; j >>= 1) {              // j in {2,1}: in-thread
            #pragma unroll
            for (int r = 0; r < 4; ++r) {
                int pr = r | j;
                if (((r & j) == 0) && pr < 4) {
                    int e = ebase + 4 * t + r;
                    bool up = ((e & k) == 0);
                    u64 a = key[r], cc = key[pr];
                    if ((a > cc) == up) { key[r] = cc; key[pr] = a; }
                }
            }
        }
    }

    #pragma unroll
    for (int r = 0; r < 4; ++r)
        keyb[(size_t)b * NMS_N + ebase + 4 * t + r] = key[r];
}

// ---------------------------------------------------------------------------
// K1b: merge stages k=2048,4096 (1 block/batch), then epilogue: sorted idx +
// corners (floor(w/2) exactly per reference) + HALF-areas (exact).
// ---------------------------------------------------------------------------
__global__ __launch_bounds__(1024) void nms_sort_merge(
        const float* __restrict__ in, const u64* __restrict__ keyb,
        u32* __restrict__ sortedIdx, float4* __restrict__ crn,
        float* __restrict__ ha) {
    __shared__ u64 sm[5120];                   // slot(4095)=5118, 41 KB
    const int b = blockIdx.x, t = threadIdx.x;
    u64 key[4];

    #pragma unroll
    for (int r = 0; r < 4; ++r)
        key[r] = keyb[(size_t)b * NMS_N + 4 * t + r];

    for (int k = 2048; k <= 4096; k <<= 1) {
        int j = k >> 1;
        if (j >= 256) {
            #pragma unroll
            for (int r = 0; r < 4; ++r) sm[lds_slot(4 * t + r)] = key[r];
            __syncthreads();
            for (; j >= 256; j >>= 1) {
                for (int e = t; e < NMS_N; e += 1024) {
                    int p = e ^ j;
                    if (p > e) {
                        u64 a = sm[lds_slot(e)], cc = sm[lds_slot(p)];
                        bool up = ((e & k) == 0);
                        if ((a > cc) == up) { sm[lds_slot(e)] = cc; sm[lds_slot(p)] = a; }
                    }
                }
                __syncthreads();
            }
            #pragma unroll
            for (int r = 0; r < 4; ++r) key[r] = sm[lds_slot(4 * t + r)];
        }
        for (; j >= 4; j >>= 1) {
            int d = j >> 2;
            #pragma unroll
            for (int r = 0; r < 4; ++r) {
                int e = 4 * t + r;
                u64 mine = key[r];
                u64 part = __shfl_xor(mine, d, 64);
                bool up = ((e & k) == 0);
                bool lower = ((e & j) == 0);
                u64 mn = (mine < part) ? mine : part;
                u64 mx = (mine < part) ? part : mine;
                key[r] = (up == lower) ? mn : mx;
            }
        }
        for (; j >= 1; j >>= 1) {
            #pragma unroll
            for (int r = 0; r < 4; ++r) {
                int pr = r | j;
                if (((r & j) == 0) && pr < 4) {
                    int e = 4 * t + r;
                    bool up = ((e & k) == 0);
                    u64 a = key[r], cc = key[pr];
                    if ((a > cc) == up) { key[r] = cc; key[pr] = a; }
                }
            }
        }
    }

    #pragma unroll
    for (int r = 0; r < 4; ++r) {
        int e = 4 * t + r;
        u32 orig = (u32)key[r];
        const float* bp = in + ((size_t)b * NMS_N + orig) * 5;
        float x = bp[1], y = bp[2], w = bp[3], h = bp[4];
        float ws_ = floorf(w * 0.5f);
        float hs_ = floorf(h * 0.5f);
        float X1 = x - ws_, Y1 = y - hs_, X2 = x + ws_, Y2 = y + hs_;
        size_t g = (size_t)b * NMS_N + e;
        sortedIdx[g] = orig;
        crn[g] = make_float4(X1, Y1, X2, Y2);
        ha[g] = 0.5f * ((X2 - X1) * (Y2 - Y1));   // exact: area is a small int
    }
}

// ---------------------------------------------------------------------------
// K2: suppression bitmask, ballot orientation, equal-work trapezoid grid.
// NEW: the two diagonal units per wp (rowblk==2wp, 2wp+1) additionally write
// the dense diag-block array diagw2[b][wp][r] = words (2wp,2wp+1) of row
// 128*wp+r  (r=0..127) — 16 B/lane coalesced. These words are FULLY computed
// (all 128 cols), so all bits are valid IoU results.
// ---------------------------------------------------------------------------
__global__ __launch_bounds__(256) void nms_mask(
        const float4* __restrict__ crn, const float* __restrict__ ha,
        u64* __restrict__ mask, u64* __restrict__ diagw2) {
    const int b = blockIdx.y;
    const int u = blockIdx.x * 4 + (threadIdx.x >> 6);   // unit id, 0..1055
    const int lane = threadIdx.x & 63;

    int wp = (int)sqrtf((float)u);
    while (wp * (wp + 1) > u) --wp;
    while ((wp + 1) * (wp + 2) <= u) ++wp;
    const int rowblk = u - wp * (wp + 1);                // 0..2*wp+1

    const size_t base = (size_t)b * NMS_N;
    const int c0 = wp * 128 + lane;
    float4 c0c = crn[base + c0];
    float4 c1c = crn[base + c0 + 64];
    float h0 = ha[base + c0];
    float h1 = ha[base + c0 + 64];

    const int rowbase = __builtin_amdgcn_readfirstlane(rowblk * 64);
    const float4* rowc = crn + base + rowbase;
    const float* rowh = ha + base + rowbase;

    u64 w0 = 0, w1 = 0;
    for (int rg = 0; rg < 64; rg += 8) {
        float fx1[8], fy1[8], fx2[8], fy2[8], fha[8];
        #pragma unroll
        for (int q = 0; q < 8; ++q) {                    // uniform -> s_load
            float4 rc = rowc[rg + q];
            fx1[q] = rc.x; fy1[q] = rc.y; fx2[q] = rc.z; fy2[q] = rc.w;
            fha[q] = rowh[rg + q];
        }
        #pragma unroll
        for (int q = 0; q < 8; ++q) {
            float iw0 = fmaxf(fminf(fx2[q], c0c.z) - fmaxf(fx1[q], c0c.x), 0.0f);
            float ih0 = fmaxf(fminf(fy2[q], c0c.w) - fmaxf(fy1[q], c0c.y), 0.0f);
            float in0 = iw0 * ih0;
            bool p0 = in0 > fmaf(-0.5f, in0, fha[q] + h0);

            float iw1 = fmaxf(fminf(fx2[q], c1c.z) - fmaxf(fx1[q], c1c.x), 0.0f);
            float ih1 = fmaxf(fminf(fy2[q], c1c.w) - fmaxf(fy1[q], c1c.y), 0.0f);
            float in1 = iw1 * ih1;
            bool p1 = in1 > fmaf(-0.5f, in1, fha[q] + h1);

            u64 b0 = __ballot(p0);
            u64 b1 = __ballot(p1);
            if (lane == rg + q) { w0 = b0; w1 = b1; }
        }
    }

    ulonglong2 v; v.x = w0; v.y = w1;
    *(ulonglong2*)&mask[(base + rowbase + lane) * NMS_NW + wp * 2] = v;

    if (rowblk == 2 * wp || rowblk == 2 * wp + 1) {      // diagonal unit
        int r = ((rowblk & 1) << 6) + lane;              // row offset in 128-window
        *(ulonglong2*)&diagw2[(((size_t)b * 32 + wp) * 128 + r) * 2] = v;
    }
}

// ---------------------------------------------------------------------------
// K3 v5: one wave per batch, stateless-window greedy scan, 128-row windows.
// Per window W (rows 128W..128W+127, words 2W/2W+1):
//   nextdiag: DENSE coalesced load from diagw2 (prefetched, cheap — no more
//             512B-stride 64-line gathers).
//   curwin:   OR over all kept rows so far of their word-pair (4-wide
//             ulonglong2 gather over kept[] + shfl OR-butterfly).
//   serial scalar ctz loop, word0 fully first (word0 keeps suppress word1;
//   word1 never affects word0 since only j>i bits matter). Self-bit cleared
//   explicitly. Kept bits per window held in registers (lane W), kept[]
//   positions in LDS feed the gathers.
// ---------------------------------------------------------------------------
__global__ __launch_bounds__(64, 1) void nms_scan(
        const float* __restrict__ in, const u64* __restrict__ mask,
        const u64* __restrict__ diagw2, const u32* __restrict__ sortedIdx,
        float* __restrict__ outp) {
    const int b = blockIdx.x, lane = threadIdx.x;
    const u64* M = mask + (size_t)b * NMS_N * NMS_NW;
    const u64* D = diagw2 + (size_t)b * 32 * 128 * 2;

    __shared__ int kept[ROIS];

    u64 mk0 = 0, mk1 = 0;                      // this lane's window kept bits
    int count = 0;

    // diag for window 0: dA = rows 0..63, dB = rows 64..127 (word pair each)
    ulonglong2 dA = *(const ulonglong2*)&D[(size_t)lane * 2];
    ulonglong2 dB = *(const ulonglong2*)&D[(size_t)(64 + lane) * 2];

    for (int W = 0; W < 32; ++W) {
        ulonglong2 nA, nB;
        nA.x = nA.y = nB.x = nB.y = 0;
        if (W + 1 < 32) {                      // cheap dense prefetch
            const u64* Dn = D + (size_t)(W + 1) * 128 * 2;
            nA = *(const ulonglong2*)&Dn[(size_t)lane * 2];
            nB = *(const ulonglong2*)&Dn[(size_t)(64 + lane) * 2];
        }

        // ---- curwin: OR of kept rows' words (2W, 2W+1) ----
        u64 a0 = 0, a1 = 0;
        if (count > 0) {
            const int cm1 = count - 1;
            #pragma unroll
            for (int s = 0; s < 4; ++s) {
                int j = lane + s * 64;
                int jj = j <= cm1 ? j : cm1;
                int pos = kept[jj];
                ulonglong2 v = *(const ulonglong2*)&M[(size_t)pos * NMS_NW + 2 * W];
                if (j <= cm1) { a0 |= v.x; a1 |= v.y; }
            }
            #pragma unroll
            for (int d2 = 1; d2 < 64; d2 <<= 1) {
                a0 |= (u64)__shfl_xor((long long)a0, d2, 64);
                a1 |= (u64)__shfl_xor((long long)a1, d2, 64);
            }
        }

        u64 avail0 = ~rdfirst_u64(a0);
        u64 avail1 = ~rdfirst_u64(a1);
        u64 km0 = 0, km1 = 0;

        // word 0 rows (suppress both words)
        while (avail0 != 0 && count < ROIS) {
            int r = __builtin_ctzll(avail0);
            u64 dx = rdlane_u64(dA.x, r);
            u64 dy = rdlane_u64(dA.y, r);
            if (lane == 0) kept[count] = W * 128 + r;
            km0 |= (1ULL << r);
            ++count;
            avail0 &= ~(dx | (1ULL << r));
            avail1 &= ~dy;
        }
        // word 1 rows (only word-1 bits matter: j>i)
        while (avail1 != 0 && count < ROIS) {
            int r = __builtin_ctzll(avail1);
            u64 dy = rdlane_u64(dB.y, r);
            if (lane == 0) kept[count] = W * 128 + 64 + r;
            km1 |= (1ULL << r);
            ++count;
            avail1 &= ~(dy | (1ULL << r));
        }

        if (lane == W) { mk0 = km0; mk1 = km1; }
        if (count >= ROIS) break;
        dA = nA; dB = nB;
    }

    // epilogue: register kept-bits -> output (count==256 for this workload)
    int cnt = (int)(__popcll(mk0) + __popcll(mk1));
    int pre = cnt;
    #pragma unroll
    for (int d = 1; d < 64; d <<= 1) {
        int tsum = __shfl_up(pre, d, 64);
        if (lane >= d) pre += tsum;
    }
    pre -= cnt;                                // exclusive prefix over lanes
    int slot = pre;
    #pragma unroll
    for (int half = 0; half < 2; ++half) {
        u64 bits = half ? mk1 : mk0;
        while (bits != 0) {
            int r = __builtin_ctzll(bits); bits &= bits - 1;
            if (slot < ROIS) {
                int pos = lane * 128 + half * 64 + r;
                int orig = (int)sortedIdx[(size_t)b * NMS_N + pos];
                const float* bp = in + ((size_t)b * NMS_N + orig) * 5;
                float4 o = make_float4(bp[1], bp[2], bp[3], bp[4]);
                ((float4*)outp)[(size_t)b * ROIS + slot] = o;
            }
            ++slot;
        }
    }
}

extern "C" void kernel_launch(void* const* d_in, const int* in_sizes, int n_in,
                              void* d_out, int out_size, void* d_ws, size_t ws_size,
                              hipStream_t stream) {
    const float* in = (const float*)d_in[0];
    float* out = (float*)d_out;
    char* ws = (char*)d_ws;

    u64* mask = (u64*)ws;                                          // 16 MB
    size_t off = (size_t)NMS_B * NMS_N * NMS_NW * sizeof(u64);
    u32* sortedIdx = (u32*)(ws + off); off += (size_t)NMS_B * NMS_N * 4;
    float4* crn = (float4*)(ws + off); off += (size_t)NMS_B * NMS_N * 16;
    float* ha = (float*)(ws + off);    off += (size_t)NMS_B * NMS_N * 4;
    u64* keyb = (u64*)(ws + off);      off += (size_t)NMS_B * NMS_N * 8;
    u64* diagw2 = (u64*)(ws + off);    off += (size_t)NMS_B * 32 * 128 * 2 * 8;

    nms_sort_local<<<dim3(4, NMS_B), 256, 0, stream>>>(in, keyb);
    nms_sort_merge<<<NMS_B, 1024, 0, stream>>>(in, keyb, sortedIdx, crn, ha);
    nms_mask<<<dim3(264, NMS_B), 256, 0, stream>>>(crn, ha, mask, diagw2);
    nms_scan<<<NMS_B, 64, 0, stream>>>(in, mask, diagw2, sortedIdx, out);
}

// Round 8
// 144.593 us; speedup vs baseline: 1.2907x; 1.2907x over previous
//
#include <hip/hip_runtime.h>
#include <stdint.h>

#pragma clang fp contract(off)

#define NMS_B 8
#define NMS_N 4096
#define NMS_NW 64       // 64-bit words per suppression row
#define ROIS 256

typedef unsigned long long u64;
typedef unsigned int u32;

__device__ __forceinline__ u64 rdlane_u64(u64 v, int l) {
    u32 lo = (u32)__builtin_amdgcn_readlane((int)(u32)v, l);
    u32 hi = (u32)__builtin_amdgcn_readlane((int)(u32)(v >> 32), l);
    return ((u64)hi << 32) | lo;
}
__device__ __forceinline__ u64 rdfirst_u64(u64 v) {
    u32 lo = (u32)__builtin_amdgcn_readfirstlane((int)(u32)v);
    u32 hi = (u32)__builtin_amdgcn_readfirstlane((int)(u32)(v >> 32));
    return ((u64)hi << 32) | lo;
}
__device__ __forceinline__ int lds_slot(int e) { return e + (e >> 2); }  // 4-way max bank aliasing

// ---------------------------------------------------------------------------
// K1a: local bitonic sort of 2048-element chunks (2 chunks/batch, 16 blocks,
// 512 thr x 4 elems). key = (~score_bits)<<32 | GLOBAL idx; direction bits
// use global e, so the result is bit-identical to the monolithic bitonic
// after its k=2048 stage. 66 of 78 stages run here at 2x merge parallelism.
// ---------------------------------------------------------------------------
__global__ __launch_bounds__(512) void nms_sort_local(
        const float* __restrict__ in, u64* __restrict__ keyb) {
    __shared__ u64 sm[2560];                   // slot(2047)=2558, 20.5 KB
    const int b = blockIdx.y, c = blockIdx.x, t = threadIdx.x;
    const int ebase = c * 2048;
    u64 key[4];

    #pragma unroll
    for (int r = 0; r < 4; ++r) {
        int e = ebase + 4 * t + r;
        float s = in[((size_t)b * NMS_N + e) * 5];
        key[r] = ((u64)(~__float_as_uint(s)) << 32) | (u32)e;
    }

    for (int k = 2; k <= 2048; k <<= 1) {
        int j = k >> 1;
        if (j >= 256) {                        // j = 1024,512,256 via LDS
            #pragma unroll
            for (int r = 0; r < 4; ++r) sm[lds_slot(4 * t + r)] = key[r];
            __syncthreads();
            for (; j >= 256; j >>= 1) {
                for (int el = t; el < 2048; el += 512) {
                    int p = el ^ j;
                    if (p > el) {
                        u64 a = sm[lds_slot(el)], cc = sm[lds_slot(p)];
                        bool up = (((ebase + el) & k) == 0);
                        if ((a > cc) == up) { sm[lds_slot(el)] = cc; sm[lds_slot(p)] = a; }
                    }
                }
                __syncthreads();
            }
            #pragma unroll
            for (int r = 0; r < 4; ++r) key[r] = sm[lds_slot(4 * t + r)];
        }
        for (; j >= 4; j >>= 1) {              // cross-lane via shfl_xor
            int d = j >> 2;
            #pragma unroll
            for (int r = 0; r < 4; ++r) {
                int e = ebase + 4 * t + r;
                u64 mine = key[r];
                u64 part = __shfl_xor(mine, d, 64);
                bool up = ((e & k) == 0);
                bool lower = ((e & j) == 0);
                u64 mn = (mine < part) ? mine : part;
                u64 mx = (mine < part) ? part : mine;
                key[r] = (up == lower) ? mn : mx;
            }
        }
        for (; j >= 1; j >>= 1) {              // j in {2,1}: in-thread
            #pragma unroll
            for (int r = 0; r < 4; ++r) {
                int pr = r | j;
                if (((r & j) == 0) && pr < 4) {
                    int e = ebase + 4 * t + r;
                    bool up = ((e & k) == 0);
                    u64 a = key[r], cc = key[pr];
                    if ((a > cc) == up) { key[r] = cc; key[pr] = a; }
                }
            }
        }
    }

    #pragma unroll
    for (int r = 0; r < 4; ++r)
        keyb[(size_t)b * NMS_N + ebase + 4 * t + r] = key[r];
}

// ---------------------------------------------------------------------------
// K1b: merge stage k=4096 only (j=2048,1024,512,256 LDS + shfl/local tail),
// then epilogue: sorted idx + corners (floor(w/2) exactly per reference) +
// HALF-areas (exact: areas are small even integers).
// ---------------------------------------------------------------------------
__global__ __launch_bounds__(1024) void nms_sort_merge(
        const float* __restrict__ in, const u64* __restrict__ keyb,
        u32* __restrict__ sortedIdx, float4* __restrict__ crn,
        float* __restrict__ ha) {
    __shared__ u64 sm[5120];                   // slot(4095)=5118, 41 KB
    const int b = blockIdx.x, t = threadIdx.x;
    u64 key[4];

    #pragma unroll
    for (int r = 0; r < 4; ++r)
        key[r] = keyb[(size_t)b * NMS_N + 4 * t + r];

    {
        const int k = 4096;
        int j = k >> 1;
        #pragma unroll
        for (int r = 0; r < 4; ++r) sm[lds_slot(4 * t + r)] = key[r];
        __syncthreads();
        for (; j >= 256; j >>= 1) {            // 2048,1024,512,256
            for (int e = t; e < NMS_N; e += 1024) {
                int p = e ^ j;
                if (p > e) {
                    u64 a = sm[lds_slot(e)], cc = sm[lds_slot(p)];
                    bool up = ((e & k) == 0);
                    if ((a > cc) == up) { sm[lds_slot(e)] = cc; sm[lds_slot(p)] = a; }
                }
            }
            __syncthreads();
        }
        #pragma unroll
        for (int r = 0; r < 4; ++r) key[r] = sm[lds_slot(4 * t + r)];

        for (; j >= 4; j >>= 1) {
            int d = j >> 2;
            #pragma unroll
            for (int r = 0; r < 4; ++r) {
                int e = 4 * t + r;
                u64 mine = key[r];
                u64 part = __shfl_xor(mine, d, 64);
                bool up = ((e & k) == 0);
                bool lower = ((e & j) == 0);
                u64 mn = (mine < part) ? mine : part;
                u64 mx = (mine < part) ? part : mine;
                key[r] = (up == lower) ? mn : mx;
            }
        }
        for (; j >= 1; j >>= 1) {
            #pragma unroll
            for (int r = 0; r < 4; ++r) {
                int pr = r | j;
                if (((r & j) == 0) && pr < 4) {
                    int e = 4 * t + r;
                    bool up = ((e & k) == 0);
                    u64 a = key[r], cc = key[pr];
                    if ((a > cc) == up) { key[r] = cc; key[pr] = a; }
                }
            }
        }
    }

    #pragma unroll
    for (int r = 0; r < 4; ++r) {
        int e = 4 * t + r;
        u32 orig = (u32)key[r];
        const float* bp = in + ((size_t)b * NMS_N + orig) * 5;
        float x = bp[1], y = bp[2], w = bp[3], h = bp[4];
        float ws_ = floorf(w * 0.5f);
        float hs_ = floorf(h * 0.5f);
        float X1 = x - ws_, Y1 = y - hs_, X2 = x + ws_, Y2 = y + hs_;
        size_t g = (size_t)b * NMS_N + e;
        sortedIdx[g] = orig;
        crn[g] = make_float4(X1, Y1, X2, Y2);
        ha[g] = 0.5f * ((X2 - X1) * (Y2 - Y1));   // exact: area is a small int
    }
}

// ---------------------------------------------------------------------------
// K2: suppression bitmask, ballot orientation, equal-work trapezoid grid.
// Diagonal units (rowblk==2wp, 2wp+1) also write the dense diag array
// diagw2[b][wp][r] = words (2wp,2wp+1) of row 128*wp+r — fully computed
// words (all bits valid IoU results). Unchanged otherwise.
// ---------------------------------------------------------------------------
__global__ __launch_bounds__(256) void nms_mask(
        const float4* __restrict__ crn, const float* __restrict__ ha,
        u64* __restrict__ mask, u64* __restrict__ diagw2) {
    const int b = blockIdx.y;
    const int u = blockIdx.x * 4 + (threadIdx.x >> 6);   // unit id, 0..1055
    const int lane = threadIdx.x & 63;

    int wp = (int)sqrtf((float)u);
    while (wp * (wp + 1) > u) --wp;
    while ((wp + 1) * (wp + 2) <= u) ++wp;
    const int rowblk = u - wp * (wp + 1);                // 0..2*wp+1

    const size_t base = (size_t)b * NMS_N;
    const int c0 = wp * 128 + lane;
    float4 c0c = crn[base + c0];
    float4 c1c = crn[base + c0 + 64];
    float h0 = ha[base + c0];
    float h1 = ha[base + c0 + 64];

    const int rowbase = __builtin_amdgcn_readfirstlane(rowblk * 64);
    const float4* rowc = crn + base + rowbase;
    const float* rowh = ha + base + rowbase;

    u64 w0 = 0, w1 = 0;
    for (int rg = 0; rg < 64; rg += 8) {
        float fx1[8], fy1[8], fx2[8], fy2[8], fha[8];
        #pragma unroll
        for (int q = 0; q < 8; ++q) {                    // uniform -> s_load
            float4 rc = rowc[rg + q];
            fx1[q] = rc.x; fy1[q] = rc.y; fx2[q] = rc.z; fy2[q] = rc.w;
            fha[q] = rowh[rg + q];
        }
        #pragma unroll
        for (int q = 0; q < 8; ++q) {
            float iw0 = fmaxf(fminf(fx2[q], c0c.z) - fmaxf(fx1[q], c0c.x), 0.0f);
            float ih0 = fmaxf(fminf(fy2[q], c0c.w) - fmaxf(fy1[q], c0c.y), 0.0f);
            float in0 = iw0 * ih0;
            bool p0 = in0 > fmaf(-0.5f, in0, fha[q] + h0);

            float iw1 = fmaxf(fminf(fx2[q], c1c.z) - fmaxf(fx1[q], c1c.x), 0.0f);
            float ih1 = fmaxf(fminf(fy2[q], c1c.w) - fmaxf(fy1[q], c1c.y), 0.0f);
            float in1 = iw1 * ih1;
            bool p1 = in1 > fmaf(-0.5f, in1, fha[q] + h1);

            u64 b0 = __ballot(p0);
            u64 b1 = __ballot(p1);
            if (lane == rg + q) { w0 = b0; w1 = b1; }
        }
    }

    ulonglong2 v; v.x = w0; v.y = w1;
    *(ulonglong2*)&mask[(base + rowbase + lane) * NMS_NW + wp * 2] = v;

    if (rowblk == 2 * wp || rowblk == 2 * wp + 1) {      // diagonal unit
        int r = ((rowblk & 1) << 6) + lane;              // row offset in 128-window
        *(ulonglong2*)&diagw2[(((size_t)b * 32 + wp) * 128 + r) * 2] = v;
    }
}

// ---------------------------------------------------------------------------
// K3 = v2 (R4's best-measured scan, ~35 us) with EXACTLY ONE change:
// nextdiag comes from the dense diagw2 array (coalesced, 16 lines) instead
// of the 512B-strided 64-line mask gather. Everything else byte-identical:
// 64-row windows, stateless curwin gather over kept[], single u64
// OR-butterfly, single scalar ctz loop, kept[] in LDS.
// ---------------------------------------------------------------------------
__global__ __launch_bounds__(64, 1) void nms_scan(
        const float* __restrict__ in, const u64* __restrict__ mask,
        const u64* __restrict__ diagw2, const u32* __restrict__ sortedIdx,
        float* __restrict__ outp) {
    const int b = blockIdx.x, lane = threadIdx.x;
    const u64* M = mask + (size_t)b * NMS_N * NMS_NW;
    const u64* D = diagw2 + (size_t)b * 32 * 128 * 2;

    __shared__ int kept[ROIS];
    for (int r = lane; r < ROIS; r += 64) kept[r] = 0;   // safety fallback

    int count = 0;
    // diag for window 0 (rows 0..63, word 0): diagw2 wp=0, h=0
    u64 diag = D[(size_t)lane * 2];

    for (int W = 0; W < 64 && count < ROIS; ++W) {
        // prefetch next window's diagonal from the DENSE array
        u64 nextdiag = 0;
        if (W + 1 < 64) {
            const int Wn = W + 1, Wp = Wn >> 1, h = Wn & 1;
            nextdiag = D[((size_t)Wp * 128 + (h << 6) + lane) * 2 + h];
        }

        // ---- curwin: OR of kept rows' word W ----
        u64 curwin = 0;
        if (count > 0) {
            const int cm1 = count - 1;
            u64 acc = 0;
            #pragma unroll
            for (int s = 0; s < 4; ++s) {                // 4 independent loads
                int j = lane + s * 64;
                int jj = j <= cm1 ? j : cm1;
                int pos = kept[jj];
                u64 v = M[(size_t)pos * NMS_NW + W];
                if (j <= cm1) acc |= v;
            }
            #pragma unroll
            for (int d2 = 1; d2 < 64; d2 <<= 1)          // OR-butterfly
                acc |= (u64)__shfl_xor((long long)acc, d2, 64);
            curwin = rdfirst_u64(acc);
        }

        // ---- serial scalar ctz-skip scan of this window ----
        u64 avail = ~curwin;
        while (avail != 0 && count < ROIS) {
            int r = __builtin_ctzll(avail);
            u64 d = rdlane_u64(diag, r);
            if (lane == 0) kept[count] = W * 64 + r;
            ++count;
            avail &= ~(d | (1ULL << r));
        }

        diag = nextdiag;
    }

    __syncthreads();
    for (int r = lane; r < ROIS; r += 64) {
        int pos = kept[r];
        int orig = (int)sortedIdx[(size_t)b * NMS_N + pos];
        const float* bp = in + ((size_t)b * NMS_N + orig) * 5;
        float4 o = make_float4(bp[1], bp[2], bp[3], bp[4]);
        ((float4*)outp)[(size_t)b * ROIS + r] = o;
    }
}

extern "C" void kernel_launch(void* const* d_in, const int* in_sizes, int n_in,
                              void* d_out, int out_size, void* d_ws, size_t ws_size,
                              hipStream_t stream) {
    const float* in = (const float*)d_in[0];
    float* out = (float*)d_out;
    char* ws = (char*)d_ws;

    u64* mask = (u64*)ws;                                          // 16 MB
    size_t off = (size_t)NMS_B * NMS_N * NMS_NW * sizeof(u64);
    u32* sortedIdx = (u32*)(ws + off); off += (size_t)NMS_B * NMS_N * 4;
    float4* crn = (float4*)(ws + off); off += (size_t)NMS_B * NMS_N * 16;
    float* ha = (float*)(ws + off);    off += (size_t)NMS_B * NMS_N * 4;
    u64* keyb = (u64*)(ws + off);      off += (size_t)NMS_B * NMS_N * 8;
    u64* diagw2 = (u64*)(ws + off);    off += (size_t)NMS_B * 32 * 128 * 2 * 8;

    nms_sort_local<<<dim3(2, NMS_B), 512, 0, stream>>>(in, keyb);
    nms_sort_merge<<<NMS_B, 1024, 0, stream>>>(in, keyb, sortedIdx, crn, ha);
    nms_mask<<<dim3(264, NMS_B), 256, 0, stream>>>(crn, ha, mask, diagw2);
    nms_scan<<<NMS_B, 64, 0, stream>>>(in, mask, diagw2, sortedIdx, out);
}